// Round 8
// baseline (146.605 us; speedup 1.0000x reference)
//
#include <hip/hip_runtime.h>
#include <cstdint>
#include <cstddef>
#include <math.h>

#define CAP 2048
#define KMAX 64
#define NCHUNK 8
#define SEG 1024
#define DCUT 2.5f
#define NEG_INF (-3.402823466e+38f)

// ---------------- shared device helpers ----------------

// thread-0 serial tail (f32-faithful, proven bit-exact in R7):
// top-k with ties of the kth scaled value, numpy pairwise-8 softmax denom,
// f32 sequential cdf vs raw f32 top_p, probs e/D. Inputs: sorted s_cv (desc).
__device__ __forceinline__ int tail_select(
        const float* s_cv, float* s_p, int ncand, int kwant, int topk,
        float topp) {
    int kp = 0;
    if (ncand > 0) {
        int klim = min(kwant, ncand);
        if (topk > 0 && ncand >= kwant) {
            const float kth = s_cv[kwant - 1];
            while (klim < ncand && klim < KMAX && s_cv[klim] == kth) klim++;
        }
        const float sv0 = s_cv[0];
        float e[KMAX];
        for (int j = 0; j < klim; ++j)
            e[j] = (float)exp((double)(s_cv[j] - sv0));
        float r[8] = {0.f, 0.f, 0.f, 0.f, 0.f, 0.f, 0.f, 0.f};
        for (int i = 0; i < 128; i += 8)
            #pragma unroll
            for (int j2 = 0; j2 < 8; ++j2) {
                int idx = i + j2;
                if (idx < klim) r[j2] = r[j2] + e[idx];
            }
        const float S = ((r[0] + r[1]) + (r[2] + r[3])) +
                        ((r[4] + r[5]) + (r[6] + r[7]));
        if (topp > 0.f) {
            float cdf = 0.f;
            for (int j = 0; j < klim; ++j) {
                if (j > 0 && cdf > topp) break;
                kp++;
                cdf = cdf + (float)(e[j] / S);
            }
        } else {
            kp = klim;
        }
        float D = 0.f;
        for (int j = 0; j < kp; ++j) D = D + e[j];
        if (!(D > 0.f)) D = 1.f;
        for (int j = 0; j < kp; ++j) s_p[j] = e[j] / D;
    }
    return kp;
}

// bitonic sort of s_cv/s_ci[0..sortn): value desc, index asc (stable argsort(-x))
__device__ __forceinline__ void bitonic_sort(
        float* s_cv, unsigned int* s_ci, int sortn, int tid, int nthr) {
    for (unsigned int size = 2; size <= (unsigned)sortn; size <<= 1) {
        for (unsigned int stride = size >> 1; stride > 0; stride >>= 1) {
            for (int i = tid; i < sortn / 2; i += nthr) {
                unsigned int ui = (unsigned int)i;
                unsigned int pos = 2u * ui - (ui & (stride - 1u));
                unsigned int a = pos, b = pos + stride;
                float va = s_cv[a], vb = s_cv[b];
                unsigned int ia = s_ci[a], ib = s_ci[b];
                bool aBeforeB = (va > vb) || (va == vb && ia < ib);
                bool bBeforeA = (vb > va) || (vb == va && ib < ia);
                bool descBlock = ((pos & size) == 0u);
                bool doSwap = descBlock ? bBeforeA : aBeforeB;
                if (doSwap) {
                    s_cv[a] = vb; s_cv[b] = va;
                    s_ci[a] = ib; s_ci[b] = ia;
                }
            }
            __syncthreads();
        }
    }
}

// ---------------- Kernel A: stream once ----------------
// zero output, per-chunk scaled max, speculative candidates >= chunkmax - DCUT.
// ws layout: [0, BN) u32 counts | [BN, 2*BN) f32 chunkmax | then BN segs of
// SEG (f32 val, u32 idx) pairs.  BN = B*NCHUNK.
__global__ __launch_bounds__(256) void k_stream(
        const float* __restrict__ in, float* __restrict__ out,
        unsigned int* __restrict__ ws_cnt, float* __restrict__ ws_max,
        float2* __restrict__ ws_cand, const float* __restrict__ tempP,
        int nv4) {
    __shared__ float s_w[4];
    __shared__ unsigned int s_cnt;
    __shared__ float s_T;
    const int row = blockIdx.x / NCHUNK;
    const int chunk = blockIdx.x % NCHUNK;
    const int c4 = (nv4 + NCHUNK - 1) / NCHUNK;
    const int base = chunk * c4;
    const int end = min(nv4, base + c4);
    const int tid = (int)threadIdx.x;
    const float t = tempP[0];
    const bool doT = (t > 0.f);

    const float4* in4 = (const float4*)in + (size_t)row * nv4;
    float4* out4 = (float4*)out + (size_t)row * nv4;

    if (tid == 0) s_cnt = 0u;
    float m = NEG_INF;
    for (int i = base + tid; i < end; i += 256) {
        float4 v = in4[i];
        out4[i] = make_float4(0.f, 0.f, 0.f, 0.f);
        float a = doT ? v.x / t : v.x;
        float b = doT ? v.y / t : v.y;
        float c = doT ? v.z / t : v.z;
        float d = doT ? v.w / t : v.w;
        m = fmaxf(m, fmaxf(fmaxf(a, b), fmaxf(c, d)));
    }
    #pragma unroll
    for (int off = 32; off; off >>= 1)
        m = fmaxf(m, __shfl_xor(m, off));
    if ((tid & 63) == 0) s_w[tid >> 6] = m;
    __syncthreads();
    if (tid == 0) {
        float cm = fmaxf(fmaxf(s_w[0], s_w[1]), fmaxf(s_w[2], s_w[3]));
        ws_max[blockIdx.x] = cm;
        s_T = cm - DCUT;
    }
    __syncthreads();

    const float T = s_T;
    float2* seg = ws_cand + (size_t)blockIdx.x * SEG;
    for (int i = base + tid; i < end; i += 256) {
        float4 v = in4[i];  // L1/L2-hot re-read of this block's own chunk
        float xs[4];
        xs[0] = doT ? v.x / t : v.x;
        xs[1] = doT ? v.y / t : v.y;
        xs[2] = doT ? v.z / t : v.z;
        xs[3] = doT ? v.w / t : v.w;
        #pragma unroll
        for (int c2 = 0; c2 < 4; ++c2) {
            if (xs[c2] >= T) {
                unsigned int slot = atomicAdd(&s_cnt, 1u);
                if (slot < (unsigned)SEG) {
                    float2 p;
                    p.x = xs[c2];
                    p.y = __uint_as_float((unsigned int)(4 * i + c2));
                    seg[slot] = p;
                }
            }
        }
    }
    __syncthreads();
    if (tid == 0) ws_cnt[blockIdx.x] = s_cnt;  // may exceed SEG -> overflow flag
}

// ---------------- Kernel B: per-row select ----------------
__global__ __launch_bounds__(1024) void k_select(
        const float* __restrict__ in, float* __restrict__ out,
        const unsigned int* __restrict__ ws_cnt, const float* __restrict__ ws_max,
        const float2* __restrict__ ws_cand, const float* __restrict__ tempP,
        const int* __restrict__ topkP, const float* __restrict__ toppP,
        int V, int nv4) {
    __shared__ float s_cv[CAP];
    __shared__ unsigned int s_ci[CAP];
    __shared__ unsigned int s_cnt;
    __shared__ float s_p[KMAX];
    __shared__ int s_kp;

    const int row = blockIdx.x;
    const int tid = (int)threadIdx.x;
    const int nthr = (int)blockDim.x;

    const float t = tempP[0];
    const bool doT = (t > 0.f);
    int topk = topkP[0];
    if (topk < 0 || topk > V) topk = 0;
    const float topp = toppP[0];
    const int kwant = (topk > 0) ? min(topk, KMAX) : KMAX;

    // row max + overflow check from kernel A results
    float M = NEG_INF;
    bool overflow = false;
    #pragma unroll
    for (int c = 0; c < NCHUNK; ++c) {
        M = fmaxf(M, ws_max[row * NCHUNK + c]);
        if (ws_cnt[row * NCHUNK + c] > (unsigned)SEG) overflow = true;
    }

    // fast path: gather pre-collected candidates, filter to >= M - DCUT
    unsigned int cnt = 0;
    if (!overflow) {
        if (tid == 0) s_cnt = 0u;
        __syncthreads();
        const float T = M - DCUT;
        for (int c = 0; c < NCHUNK; ++c) {
            const int cc = (int)ws_cnt[row * NCHUNK + c];
            const float2* seg = ws_cand + (size_t)(row * NCHUNK + c) * SEG;
            for (int j = tid; j < cc; j += nthr) {
                float2 p = seg[j];
                if (p.x >= T) {
                    unsigned int slot = atomicAdd(&s_cnt, 1u);
                    if (slot < (unsigned)CAP) {
                        s_cv[slot] = p.x;
                        s_ci[slot] = __float_as_uint(p.y);
                    }
                }
            }
        }
        __syncthreads();
        cnt = s_cnt;
        __syncthreads();
    }

    // fallback: full-row adaptive collection (rare; correctness safety net)
    if (overflow || cnt < (unsigned)kwant || cnt > (unsigned)CAP) {
        const float4* in4 = (const float4*)in + (size_t)row * nv4;
        float dcut = DCUT;
        for (int round = 0; round < 14; ++round) {
            if (tid == 0) s_cnt = 0u;
            __syncthreads();
            const float T = M - dcut;
            for (int i = tid; i < nv4; i += nthr) {
                float4 v = in4[i];
                float xs[4];
                xs[0] = doT ? v.x / t : v.x;
                xs[1] = doT ? v.y / t : v.y;
                xs[2] = doT ? v.z / t : v.z;
                xs[3] = doT ? v.w / t : v.w;
                #pragma unroll
                for (int c2 = 0; c2 < 4; ++c2) {
                    if (xs[c2] >= T) {
                        unsigned int slot = atomicAdd(&s_cnt, 1u);
                        if (slot < (unsigned)CAP) {
                            s_cv[slot] = xs[c2];
                            s_ci[slot] = (unsigned int)(4 * i + c2);
                        }
                    }
                }
            }
            __syncthreads();
            cnt = s_cnt;
            __syncthreads();
            if (cnt >= (unsigned)kwant && cnt <= (unsigned)CAP) break;
            if (round == 13) break;
            dcut = (cnt < (unsigned)kwant) ? (dcut * 2.0f) : (dcut * 0.4f);
        }
    }
    const int ncand = (int)min(cnt, (unsigned)CAP);

    // dynamic sort width: smallest pow2 >= max(ncand, 128), capped at CAP
    int sortn = 128;
    while (sortn < ncand) sortn <<= 1;

    for (int s = ncand + tid; s < sortn; s += nthr) {
        s_cv[s] = NEG_INF;
        s_ci[s] = 0xFFFFFFFFu;
    }
    __syncthreads();

    bitonic_sort(s_cv, s_ci, sortn, tid, nthr);

    if (tid == 0) s_kp = tail_select(s_cv, s_p, ncand, kwant, topk, topp);
    __syncthreads();

    if (tid < s_kp) {
        unsigned int tok = s_ci[tid];
        if (tok < (unsigned int)V)
            out[(size_t)row * V + tok] = s_p[tid];
    }
}

// ---------------- monolithic fallback (R7, proven) for tiny ws ----------------
__global__ __launch_bounds__(1024) void k_row_mono(
        const float* __restrict__ in, float* __restrict__ out,
        const float* __restrict__ tempP, const int* __restrict__ topkP,
        const float* __restrict__ toppP, int V, int nv4) {
    __shared__ float s_red[1024];
    __shared__ float s_cv[CAP];
    __shared__ unsigned int s_ci[CAP];
    __shared__ unsigned int s_cnt;
    __shared__ float s_p[KMAX];
    __shared__ int s_kp;

    const int row = blockIdx.x;
    const int tid = (int)threadIdx.x;
    const int nthr = (int)blockDim.x;

    const float t = tempP[0];
    const bool doT = (t > 0.f);
    int topk = topkP[0];
    if (topk < 0 || topk > V) topk = 0;
    const float topp = toppP[0];

    const float4* in4 = (const float4*)in + (size_t)row * nv4;
    float4* out4 = (float4*)out + (size_t)row * nv4;
    float m = NEG_INF;
    for (int i = tid; i < nv4; i += nthr) {
        float4 v = in4[i];
        out4[i] = make_float4(0.f, 0.f, 0.f, 0.f);
        float a = doT ? v.x / t : v.x;
        float b = doT ? v.y / t : v.y;
        float c = doT ? v.z / t : v.z;
        float d = doT ? v.w / t : v.w;
        m = fmaxf(m, fmaxf(fmaxf(a, b), fmaxf(c, d)));
    }
    s_red[tid] = m;
    __syncthreads();
    for (int s = 512; s > 0; s >>= 1) {
        if (tid < s) s_red[tid] = fmaxf(s_red[tid], s_red[tid + s]);
        __syncthreads();
    }
    const float M = s_red[0];
    __syncthreads();

    const int kwant = (topk > 0) ? min(topk, KMAX) : KMAX;
    float dcut = DCUT;
    unsigned int cnt = 0;
    for (int round = 0; round < 14; ++round) {
        if (tid == 0) s_cnt = 0u;
        __syncthreads();
        const float T = M - dcut;
        for (int i = tid; i < nv4; i += nthr) {
            float4 v = in4[i];
            float xs[4];
            xs[0] = doT ? v.x / t : v.x;
            xs[1] = doT ? v.y / t : v.y;
            xs[2] = doT ? v.z / t : v.z;
            xs[3] = doT ? v.w / t : v.w;
            #pragma unroll
            for (int c2 = 0; c2 < 4; ++c2) {
                if (xs[c2] >= T) {
                    unsigned int slot = atomicAdd(&s_cnt, 1u);
                    if (slot < (unsigned)CAP) {
                        s_cv[slot] = xs[c2];
                        s_ci[slot] = (unsigned int)(4 * i + c2);
                    }
                }
            }
        }
        __syncthreads();
        cnt = s_cnt;
        __syncthreads();
        if (cnt >= (unsigned)kwant && cnt <= (unsigned)CAP) break;
        if (round == 13) break;
        dcut = (cnt < (unsigned)kwant) ? (dcut * 2.0f) : (dcut * 0.4f);
    }
    const int ncand = (int)min(cnt, (unsigned)CAP);

    for (int s = ncand + tid; s < CAP; s += nthr) {
        s_cv[s] = NEG_INF;
        s_ci[s] = 0xFFFFFFFFu;
    }
    __syncthreads();
    bitonic_sort(s_cv, s_ci, CAP, tid, nthr);

    if (tid == 0) s_kp = tail_select(s_cv, s_p, ncand, kwant, topk, topp);
    __syncthreads();

    if (tid < s_kp) {
        unsigned int tok = s_ci[tid];
        if (tok < (unsigned int)V)
            out[(size_t)row * V + tok] = s_p[tid];
    }
}

extern "C" void kernel_launch(void* const* d_in, const int* in_sizes, int n_in,
                              void* d_out, int out_size, void* d_ws, size_t ws_size,
                              hipStream_t stream) {
    const float* in = (const float*)d_in[0];
    const float* tempP = (const float*)d_in[2];
    const int* topkP = (const int*)d_in[3];
    const float* toppP = (const float*)d_in[4];
    float* out = (float*)d_out;

    int B = (n_in > 1 && in_sizes[1] > 0) ? in_sizes[1] : 128;
    int V = in_sizes[0] / B;
    int nv4 = V / 4;
    const int BN = B * NCHUNK;

    // ws layout: counts (BN u32) | chunkmax (BN f32) | candidates (BN*SEG float2)
    const size_t need = (size_t)BN * 4 + (size_t)BN * 4 + (size_t)BN * SEG * 8;
    if (ws_size >= need) {
        unsigned int* ws_cnt = (unsigned int*)d_ws;
        float* ws_max = (float*)((char*)d_ws + (size_t)BN * 4);
        float2* ws_cand = (float2*)((char*)d_ws + (size_t)BN * 8);
        k_stream<<<BN, 256, 0, stream>>>(in, out, ws_cnt, ws_max, ws_cand,
                                         tempP, nv4);
        k_select<<<B, 1024, 0, stream>>>(in, out, ws_cnt, ws_max, ws_cand,
                                         tempP, topkP, toppP, V, nv4);
    } else {
        k_row_mono<<<B, 1024, 0, stream>>>(in, out, tempP, topkP, toppP, V, nv4);
    }
}